// Round 13
// baseline (169.010 us; speedup 1.0000x reference)
//
#include <hip/hip_runtime.h>
#include <hip/hip_fp8.h>

#define NHALF 4096
#define NROWS 8192
#define D 512
#define BM 128
#define BKB 128                    // K-depth per tile in fp8 bytes
#define NKT (D / BKB)              // 4 K-steps
#define NB (NROWS / BM)            // 64
#define NTRI (NB * (NB + 1) / 2)   // 2080 (divisible by 8)
#define CONV_BLOCKS 128
#define LOG2E 1.4426950408889634

typedef float f32x4 __attribute__((ext_vector_type(4)));

__device__ __forceinline__ const float* row_ptr(const float* __restrict__ src,
                                                const float* __restrict__ tgt, int r) {
    return (r < NHALF) ? (src + (size_t)r * D) : (tgt + (size_t)(r - NHALF) * D);
}

// --- Pass A: fused convert fp32->fp8(e4m3, XOR-swizzle baked) + rowsq + colsum + sumsq + bw ---
__global__ __launch_bounds__(256)
void conv_stats(const float* __restrict__ src, const float* __restrict__ tgt,
                unsigned char* __restrict__ tot8, float* __restrict__ sq,
                float* __restrict__ colsum, double* __restrict__ sumsq,
                unsigned* __restrict__ ticket, float* __restrict__ c2p_out) {
    __shared__ float cs_lds[4][512];
    __shared__ float wssq[4];
    __shared__ int lastFlag;
    __shared__ double red[256];
    int t = threadIdx.x, l = t & 63, w = t >> 6;
    int rbase = blockIdx.x * 64 + w * 16;

    float cs[8] = {0.f, 0.f, 0.f, 0.f, 0.f, 0.f, 0.f, 0.f};
    float ssq = 0.f;

    for (int rr = 0; rr < 16; ++rr) {
        int r = rbase + rr;
        const float* p = row_ptr(src, tgt, r) + l * 8;
        float4 v0 = *(const float4*)p;
        float4 v1 = *(const float4*)(p + 4);
        // pack 8 fp8 e4m3 bytes (unit l of row r), store at XOR-swizzled unit slot
        union { unsigned long long u; unsigned char b[8]; } q;
        q.b[0] = __hip_fp8_e4m3(v0.x).__x; q.b[1] = __hip_fp8_e4m3(v0.y).__x;
        q.b[2] = __hip_fp8_e4m3(v0.z).__x; q.b[3] = __hip_fp8_e4m3(v0.w).__x;
        q.b[4] = __hip_fp8_e4m3(v1.x).__x; q.b[5] = __hip_fp8_e4m3(v1.y).__x;
        q.b[6] = __hip_fp8_e4m3(v1.z).__x; q.b[7] = __hip_fp8_e4m3(v1.w).__x;
        unsigned dstu = (unsigned)((l & 48) | ((l & 15) ^ (r & 15)));
        *(unsigned long long*)&tot8[(size_t)r * D + dstu * 8] = q.u;

        float s8 = v0.x*v0.x + v0.y*v0.y + v0.z*v0.z + v0.w*v0.w
                 + v1.x*v1.x + v1.y*v1.y + v1.z*v1.z + v1.w*v1.w;
        ssq += s8;
        cs[0] += v0.x; cs[1] += v0.y; cs[2] += v0.z; cs[3] += v0.w;
        cs[4] += v1.x; cs[5] += v1.y; cs[6] += v1.z; cs[7] += v1.w;
        float rsum = s8;
        for (int off = 32; off > 0; off >>= 1) rsum += __shfl_down(rsum, off);
        if (l == 0) sq[r] = rsum;
    }
#pragma unroll
    for (int j = 0; j < 8; ++j) cs_lds[w][l * 8 + j] = cs[j];
    for (int off = 32; off > 0; off >>= 1) ssq += __shfl_down(ssq, off);
    if (l == 0) wssq[w] = ssq;
    __syncthreads();
    int c0 = t * 2;
    float a = cs_lds[0][c0] + cs_lds[1][c0] + cs_lds[2][c0] + cs_lds[3][c0];
    float b = cs_lds[0][c0+1] + cs_lds[1][c0+1] + cs_lds[2][c0+1] + cs_lds[3][c0+1];
    atomicAdd(&colsum[c0], a);
    atomicAdd(&colsum[c0 + 1], b);
    if (t == 0) atomicAdd(sumsq, (double)(wssq[0] + wssq[1] + wssq[2] + wssq[3]));
    __syncthreads();

    if (t == 0) {
        __threadfence();
        unsigned old = atomicAdd(ticket, 1u);
        lastFlag = (old == CONV_BLOCKS - 1) ? 1 : 0;
    }
    __syncthreads();
    if (lastFlag) {
        float ca = atomicAdd(&colsum[t], 0.f);
        float cb = atomicAdd(&colsum[t + 256], 0.f);
        red[t] = (double)ca * ca + (double)cb * cb;
        __syncthreads();
        for (int s = 128; s > 0; s >>= 1) {
            if (t < s) red[t] += red[t + s];
            __syncthreads();
        }
        if (t == 0) {
            double ssqd = atomicAdd(sumsq, 0.0);
            double m = (double)NROWS;
            double sumL2 = 2.0 * m * ssqd - 2.0 * red[0];
            double bw = sumL2 / (m * m - m) / 4.0;
            c2p_out[0] = (float)(LOG2E / (16.0 * bw));
        }
    }
}

// --- Pass B: R5 structure, fp8 data: 128x128 tile, 4 waves, 4 K-steps, 33 KB LDS ---
__global__ __launch_bounds__(256, 4)
void mmd_main(const unsigned char* __restrict__ tot8, const float* __restrict__ sq,
              const float* __restrict__ c2p_p, double* __restrict__ S,
              unsigned* __restrict__ ticket, float* __restrict__ out) {
    int b = blockIdx.x;
    int ti = (b & 7) * (NTRI / 8) + (b >> 3);   // XCD swizzle (2080 % 8 == 0, bijective)
    int bi = (int)(64.5f - sqrtf(64.5f * 64.5f - 2.0f * (float)ti));
    if (bi < 0) bi = 0;
    while (bi > 0 && bi * NB - bi * (bi - 1) / 2 > ti) --bi;
    while ((bi + 1) * NB - (bi + 1) * bi / 2 <= ti) ++bi;
    int bj = bi + (ti - (bi * NB - bi * (bi - 1) / 2));

    // LDS: row-major fp8 tile [128 rows][128 B], 8B-units XOR-swizzled (baked in global)
    __shared__ __align__(16) unsigned char As[BM * BKB];   // 16 KB
    __shared__ __align__(16) unsigned char Bs[BM * BKB];   // 16 KB

    int t = threadIdx.x, l = t & 63, w = t >> 6;
    int wr = w >> 1, wc = w & 1;       // 2x2 wave grid, 64x64 out each
    int m = l & 15, kg = l >> 4;

    const unsigned char* ab = tot8 + (size_t)(bi * BM) * D;
    const unsigned char* bb = tot8 + (size_t)(bj * BM) * D;

    f32x4 acc[4][4];
#pragma unroll
    for (int i = 0; i < 4; ++i)
#pragma unroll
        for (int j = 0; j < 4; ++j)
            acc[i][j] = (f32x4){0.f, 0.f, 0.f, 0.f};

    for (int kt = 0; kt < NKT; ++kt) {
        __syncthreads();   // previous iteration's LDS reads done
        // 1024 16-B chunks per matrix (128 rows x 8 chunks); 4 per thread; verbatim copy
#pragma unroll
        for (int i = 0; i < 4; ++i) {
            int g = i * 256 + t;
            int row = g >> 3, ch = g & 7;
            __builtin_amdgcn_global_load_lds(
                (const __attribute__((address_space(1))) void*)(ab + (size_t)row * D + kt * BKB + ch * 16),
                (__attribute__((address_space(3))) void*)(As + g * 16),
                16, 0, 0);
            __builtin_amdgcn_global_load_lds(
                (const __attribute__((address_space(1))) void*)(bb + (size_t)row * D + kt * BKB + ch * 16),
                (__attribute__((address_space(3))) void*)(Bs + g * 16),
                16, 0, 0);
        }
        __syncthreads();   // drains vmcnt(0): tile ready

#pragma unroll
        for (int ks = 0; ks < 4; ++ks) {   // 4 x K=32 fp8 MFMA slices per tile
            long af[4], bfr[4];
#pragma unroll
            for (int fi = 0; fi < 4; ++fi) {
                int row = wr * 64 + fi * 16 + m;
                int unit = (ks * 4 + kg) ^ m;          // un-swizzle on read
                af[fi] = *(const long*)&As[row * BKB + unit * 8];
            }
#pragma unroll
            for (int fj = 0; fj < 4; ++fj) {
                int row = wc * 64 + fj * 16 + m;
                int unit = (ks * 4 + kg) ^ m;
                bfr[fj] = *(const long*)&Bs[row * BKB + unit * 8];
            }
#pragma unroll
            for (int fi = 0; fi < 4; ++fi)
#pragma unroll
                for (int fj = 0; fj < 4; ++fj)
                    acc[fi][fj] = __builtin_amdgcn_mfma_f32_16x16x32_fp8_fp8(af[fi], bfr[fj], acc[fi][fj], 0, 0, 0);
        }
    }

    // Epilogue: L2 -> 5-kernel sum via exp2; exact diagonal substitution (value = 5)
    float c2p = c2p_p[0];
    float tc2 = c2p + c2p;
    float coef = ((bi == bj) ? 1.f : 2.f) * (((bi < NB / 2) == (bj < NB / 2)) ? 1.f : -1.f);

    float cj[4];
#pragma unroll
    for (int fj = 0; fj < 4; ++fj) cj[fj] = c2p * sq[bj * BM + wc * 64 + fj * 16 + m];
    int ib = bi * BM + wr * 64 + kg * 4;

    float local = 0.f;
#pragma unroll
    for (int fi = 0; fi < 4; ++fi) {
        float ci[4];
#pragma unroll
        for (int j = 0; j < 4; ++j) ci[j] = c2p * sq[ib + fi * 16 + j];
#pragma unroll
        for (int fj = 0; fj < 4; ++fj) {
#pragma unroll
            for (int j = 0; j < 4; ++j) {
                float arg = fmaf(acc[fi][fj][j], tc2, -(ci[j] + cj[fj]));
                float u = exp2f(arg);          // e^{-L2/16bw}
                float ks2 = u;
                u *= u; ks2 += u;              // /8bw
                u *= u; ks2 += u;              // /4bw
                u *= u; ks2 += u;              // /2bw
                u *= u; ks2 += u;              // /bw
                if (bi == bj) {
                    int ig = wr * 64 + fi * 16 + kg * 4 + j;
                    int jg = wc * 64 + fj * 16 + m;
                    if (ig == jg) ks2 = 5.0f;  // exact diagonal: L2 == 0 -> 5 kernels of 1
                }
                local += ks2;
            }
        }
    }
    local *= coef;

    for (int off = 32; off > 0; off >>= 1) local += __shfl_down(local, off);
    if (l == 0) atomicAdd(S, (double)local);
    __syncthreads();
    if (t == 0) {
        __threadfence();
        unsigned old = atomicAdd(ticket, 1u);
        if (old == NTRI - 1) {
            double Sv = atomicAdd(S, 0.0);
            out[0] = (float)(Sv / ((double)NHALF * (double)NHALF));
        }
    }
}

extern "C" void kernel_launch(void* const* d_in, const int* in_sizes, int n_in,
                              void* d_out, int out_size, void* d_ws, size_t ws_size,
                              hipStream_t stream) {
    const float* src = (const float*)d_in[0];
    const float* tgt = (const float*)d_in[1];
    float* out = (float*)d_out;
    char* ws = (char*)d_ws;

    // ws layout
    unsigned char* tot8 = (unsigned char*)ws;              // 4 MB (8192*512 fp8)
    float*    sq      = (float*)(ws + 4194304);            // 32768 B
    float*    colsum  = (float*)(ws + 4194304 + 32768);    // 2048 B
    double*   sumsq   = (double*)(ws + 4194304 + 34816);   // 8 B
    double*   S       = (double*)(ws + 4194304 + 34824);   // 8 B
    unsigned* ticket1 = (unsigned*)(ws + 4194304 + 34832); // 4 B
    unsigned* ticket2 = (unsigned*)(ws + 4194304 + 34836); // 4 B
    float*    c2p     = (float*)(ws + 4194304 + 34840);    // 4 B

    // zero accumulators + tickets (ws poisoned 0xAA once; not re-poisoned between replays)
    hipMemsetAsync(ws + 4194304 + 32768, 0, 2072, stream);

    conv_stats<<<CONV_BLOCKS, 256, 0, stream>>>(src, tgt, tot8, sq, colsum, sumsq, ticket1, c2p);
    mmd_main<<<NTRI, 256, 0, stream>>>(tot8, sq, c2p, S, ticket2, out);
}

// Round 14
// 99.502 us; speedup vs baseline: 1.6986x; 1.6986x over previous
//
#include <hip/hip_runtime.h>

#define NHALF 4096
#define NROWS 8192
#define D 512
#define BM 128
#define BK 64
#define NB (NROWS / BM)            // 64
#define NTRI (NB * (NB + 1) / 2)   // 2080

typedef __bf16 bf16x8 __attribute__((ext_vector_type(8)));
typedef float  f32x4  __attribute__((ext_vector_type(4)));

__device__ __forceinline__ const float* row_ptr(const float* __restrict__ src,
                                                const float* __restrict__ tgt, int r) {
    return (r < NHALF) ? (src + (size_t)r * D) : (tgt + (size_t)(r - NHALF) * D);
}

// --- Pass A: fused convert fp32->bf16 + rowsq + colsum + sumsq ---
// 128 blocks x 256 threads; block handles 64 rows, each wave 16 rows.
__global__ __launch_bounds__(256)
void conv_stats(const float* __restrict__ src, const float* __restrict__ tgt,
                __bf16* __restrict__ tot, float* __restrict__ sq,
                float* __restrict__ colsum, double* __restrict__ sumsq) {
    __shared__ float cs_lds[4][512];
    int t = threadIdx.x, l = t & 63, w = t >> 6;
    int rbase = blockIdx.x * 64 + w * 16;

    float cs[8] = {0.f, 0.f, 0.f, 0.f, 0.f, 0.f, 0.f, 0.f};
    float ssq = 0.f;

    for (int rr = 0; rr < 16; ++rr) {
        int r = rbase + rr;
        const float* p = row_ptr(src, tgt, r) + l * 8;
        float4 v0 = *(const float4*)p;
        float4 v1 = *(const float4*)(p + 4);
        bf16x8 o;
        o[0] = (__bf16)v0.x; o[1] = (__bf16)v0.y; o[2] = (__bf16)v0.z; o[3] = (__bf16)v0.w;
        o[4] = (__bf16)v1.x; o[5] = (__bf16)v1.y; o[6] = (__bf16)v1.z; o[7] = (__bf16)v1.w;
        *(bf16x8*)&tot[(size_t)r * D + l * 8] = o;
        float s8 = v0.x*v0.x + v0.y*v0.y + v0.z*v0.z + v0.w*v0.w
                 + v1.x*v1.x + v1.y*v1.y + v1.z*v1.z + v1.w*v1.w;
        ssq += s8;
        cs[0] += v0.x; cs[1] += v0.y; cs[2] += v0.z; cs[3] += v0.w;
        cs[4] += v1.x; cs[5] += v1.y; cs[6] += v1.z; cs[7] += v1.w;
        // row sum-of-squares
        float rsum = s8;
        for (int off = 32; off > 0; off >>= 1) rsum += __shfl_down(rsum, off);
        if (l == 0) sq[r] = rsum;
    }
    // colsum partials: wave -> LDS, then 2 cols per thread across 4 waves
#pragma unroll
    for (int j = 0; j < 8; ++j) cs_lds[w][l * 8 + j] = cs[j];
    // sumsq
    for (int off = 32; off > 0; off >>= 1) ssq += __shfl_down(ssq, off);
    __shared__ float wssq[4];
    if (l == 0) wssq[w] = ssq;
    __syncthreads();
    int c0 = t * 2;
    float a = cs_lds[0][c0] + cs_lds[1][c0] + cs_lds[2][c0] + cs_lds[3][c0];
    float b = cs_lds[0][c0+1] + cs_lds[1][c0+1] + cs_lds[2][c0+1] + cs_lds[3][c0+1];
    atomicAdd(&colsum[c0], a);
    atomicAdd(&colsum[c0 + 1], b);
    if (t == 0) atomicAdd(sumsq, (double)(wssq[0] + wssq[1] + wssq[2] + wssq[3]));
}

// --- Pass B: bandwidth scalar ---
__global__ void bw_kernel(const float* __restrict__ colsum, const double* __restrict__ sumsq,
                          float* __restrict__ inv16bw) {
    __shared__ double red[512];
    int c = threadIdx.x;
    double v = (double)colsum[c];
    red[c] = v * v;
    __syncthreads();
    for (int s = 256; s > 0; s >>= 1) {
        if (c < s) red[c] += red[c + s];
        __syncthreads();
    }
    if (c == 0) {
        double m = (double)NROWS;
        double sumL2 = 2.0 * m * sumsq[0] - 2.0 * red[0];
        double bw = sumL2 / (m * m - m);
        bw = bw / 4.0;  // / KERNEL_MUL^(KERNEL_NUM//2)
        inv16bw[0] = (float)(1.0 / (16.0 * bw));
    }
}

// --- Pass C: MFMA pairwise kernel, m97 structure + swizzled-source gload_lds ---
__global__ __launch_bounds__(256)
void mmd_main(const __bf16* __restrict__ tot,
              const float* __restrict__ sq, const float* __restrict__ inv16bw_p,
              double* __restrict__ S) {
    int b = blockIdx.x;
    int ti = (b & 7) * (NTRI / 8) + (b >> 3);   // XCD swizzle (2080 % 8 == 0)
    int bi = (int)(64.5f - sqrtf(64.5f * 64.5f - 2.0f * (float)ti));
    while (bi * NB - bi * (bi - 1) / 2 > ti) --bi;
    while ((bi + 1) * NB - (bi + 1) * bi / 2 <= ti) ++bi;
    int bj = bi + (ti - (bi * NB - bi * (bi - 1) / 2));

    __shared__ __align__(16) __bf16 As[BM * BK];  // 16 KB each, linear layout
    __shared__ __align__(16) __bf16 Bs[BM * BK];

    int t = threadIdx.x;
    int l = t & 63;
    int w = t >> 6;
    int wr = w >> 1, wc = w & 1;       // 2x2 wave grid, 64x64 out each
    int r0 = l & 15, kg = l >> 4;

    // staging: 16 segs of 8 rows; wave w owns segs w*4..w*4+3
    // source granule pre-swizzled so that swizzled ds_read sees correct data
    int srow_in_seg = l >> 3;                  // 0..7 == row&7
    int gsrc = (l & 7) ^ srow_in_seg;          // inverse swizzle on global source
    const __bf16* abase = tot + (size_t)(bi * BM) * D;
    const __bf16* bbase = tot + (size_t)(bj * BM) * D;

    f32x4 acc[4][4];
#pragma unroll
    for (int i = 0; i < 4; ++i)
#pragma unroll
        for (int j = 0; j < 4; ++j)
            acc[i][j] = (f32x4){0.f, 0.f, 0.f, 0.f};

    for (int k0 = 0; k0 < D; k0 += BK) {
        __syncthreads();   // previous iteration's LDS reads done
#pragma unroll
        for (int i = 0; i < 4; ++i) {
            int seg = w * 4 + i;
            int row = seg * 8 + srow_in_seg;
            __builtin_amdgcn_global_load_lds(
                (const __attribute__((address_space(1))) void*)(abase + (size_t)row * D + k0 + gsrc * 8),
                (__attribute__((address_space(3))) void*)(As + seg * 8 * BK),
                16, 0, 0);
            __builtin_amdgcn_global_load_lds(
                (const __attribute__((address_space(1))) void*)(bbase + (size_t)row * D + k0 + gsrc * 8),
                (__attribute__((address_space(3))) void*)(Bs + seg * 8 * BK),
                16, 0, 0);
        }
        __syncthreads();   // compiler drains vmcnt(0) before this barrier

#pragma unroll
        for (int ks = 0; ks < 2; ++ks) {
            bf16x8 af[4], bfr[4];
#pragma unroll
            for (int fi = 0; fi < 4; ++fi) {
                int row = wr * 64 + fi * 16 + r0;
                int g = (ks * 4 + kg) ^ (row & 7);
                af[fi] = *(const bf16x8*)&As[row * BK + g * 8];
            }
#pragma unroll
            for (int fj = 0; fj < 4; ++fj) {
                int row = wc * 64 + fj * 16 + r0;
                int g = (ks * 4 + kg) ^ (row & 7);
                bfr[fj] = *(const bf16x8*)&Bs[row * BK + g * 8];
            }
#pragma unroll
            for (int fi = 0; fi < 4; ++fi)
#pragma unroll
                for (int fj = 0; fj < 4; ++fj)
                    acc[fi][fj] = __builtin_amdgcn_mfma_f32_16x16x32_bf16(af[fi], bfr[fj], acc[fi][fj], 0, 0, 0);
        }
    }

    // Epilogue: L2 -> 5-kernel sum (1 exp + 4 squarings), signed block coef
    float inv16bw = inv16bw_p[0];
    float coef = ((bi == bj) ? 1.f : 2.f) * (((bi < NB / 2) == (bj < NB / 2)) ? 1.f : -1.f);

    float local = 0.f;
#pragma unroll
    for (int fi = 0; fi < 4; ++fi) {
#pragma unroll
        for (int fj = 0; fj < 4; ++fj) {
#pragma unroll
            for (int j = 0; j < 4; ++j) {
                int ig = bi * BM + wr * 64 + fi * 16 + (l >> 4) * 4 + j;
                int jg = bj * BM + wc * 64 + fj * 16 + (l & 15);
                float L2 = sq[ig] + sq[jg] - 2.f * acc[fi][fj][j];
                float u = __expf(-L2 * inv16bw);   // e^{-t/16}
                float ks = u;
                u *= u; ks += u;   // e^{-t/8}
                u *= u; ks += u;   // e^{-t/4}
                u *= u; ks += u;   // e^{-t/2}
                u *= u; ks += u;   // e^{-t}
                local += ks;
            }
        }
    }
    local *= coef;

    for (int off = 32; off > 0; off >>= 1) local += __shfl_down(local, off);
    __shared__ float wsum[4];
    if ((t & 63) == 0) wsum[t >> 6] = local;
    __syncthreads();
    if (t == 0) {
        float bsum = wsum[0] + wsum[1] + wsum[2] + wsum[3];
        atomicAdd(S, (double)bsum);
    }
}

__global__ void finalize_kernel(const double* __restrict__ S, float* __restrict__ out) {
    out[0] = (float)(S[0] / ((double)NHALF * (double)NHALF));
}

extern "C" void kernel_launch(void* const* d_in, const int* in_sizes, int n_in,
                              void* d_out, int out_size, void* d_ws, size_t ws_size,
                              hipStream_t stream) {
    const float* src = (const float*)d_in[0];
    const float* tgt = (const float*)d_in[1];
    float* out = (float*)d_out;
    char* ws = (char*)d_ws;

    // ws layout
    __bf16* tot     = (__bf16*)ws;                         // 8 MB  (8192*512*2)
    float*  sq      = (float*)(ws + 8388608);              // 32768 B
    float*  colsum  = (float*)(ws + 8388608 + 32768);      // 2048 B
    double* sumsq   = (double*)(ws + 8388608 + 34816);     // 8 B
    double* S       = (double*)(ws + 8388608 + 34824);     // 8 B
    float*  inv16bw = (float*)(ws + 8388608 + 34832);      // 4 B

    // zero accumulators (ws poisoned 0xAA, not re-poisoned between replays)
    hipMemsetAsync(ws + 8388608 + 32768, 0, 2068, stream);

    conv_stats<<<128, 256, 0, stream>>>(src, tgt, tot, sq, colsum, sumsq);
    bw_kernel<<<1, 512, 0, stream>>>(colsum, sumsq, inv16bw);
    mmd_main<<<NTRI, 256, 0, stream>>>(tot, sq, inv16bw, S);
    finalize_kernel<<<1, 1, 0, stream>>>(S, out);
}

// Round 15
// 73.731 us; speedup vs baseline: 2.2923x; 1.3495x over previous
//
#include <hip/hip_runtime.h>
#include <hip/hip_fp8.h>

#define NHALF 4096
#define NROWS 8192
#define D 512
#define BM 128
#define BKB 128                    // K-depth per tile in fp8 bytes
#define NKT (D / BKB)              // 4 K-steps
#define NB (NROWS / BM)            // 64
#define NTRI (NB * (NB + 1) / 2)   // 2080 (divisible by 8)

typedef float f32x4 __attribute__((ext_vector_type(4)));

__device__ __forceinline__ const float* row_ptr(const float* __restrict__ src,
                                                const float* __restrict__ tgt, int r) {
    return (r < NHALF) ? (src + (size_t)r * D) : (tgt + (size_t)(r - NHALF) * D);
}

// --- Pass A: fused convert fp32->fp8 e4m3 (XOR-swizzle baked) + rowsq + colsum + sumsq ---
__global__ __launch_bounds__(256)
void conv_stats(const float* __restrict__ src, const float* __restrict__ tgt,
                unsigned char* __restrict__ tot8, float* __restrict__ sq,
                float* __restrict__ colsum, double* __restrict__ sumsq) {
    __shared__ float cs_lds[4][512];
    int t = threadIdx.x, l = t & 63, w = t >> 6;
    int rbase = blockIdx.x * 64 + w * 16;

    float cs[8] = {0.f, 0.f, 0.f, 0.f, 0.f, 0.f, 0.f, 0.f};
    float ssq = 0.f;

    for (int rr = 0; rr < 16; ++rr) {
        int r = rbase + rr;
        const float* p = row_ptr(src, tgt, r) + l * 8;
        float4 v0 = *(const float4*)p;
        float4 v1 = *(const float4*)(p + 4);
        // pack 8 fp8 e4m3 bytes (unit l of row r); store at XOR-swizzled unit slot
        union { unsigned long long u; unsigned char b[8]; } q;
        q.b[0] = __hip_fp8_e4m3(v0.x).__x; q.b[1] = __hip_fp8_e4m3(v0.y).__x;
        q.b[2] = __hip_fp8_e4m3(v0.z).__x; q.b[3] = __hip_fp8_e4m3(v0.w).__x;
        q.b[4] = __hip_fp8_e4m3(v1.x).__x; q.b[5] = __hip_fp8_e4m3(v1.y).__x;
        q.b[6] = __hip_fp8_e4m3(v1.z).__x; q.b[7] = __hip_fp8_e4m3(v1.w).__x;
        unsigned dstu = (unsigned)((l & 48) | ((l & 15) ^ (r & 15)));
        *(unsigned long long*)&tot8[(size_t)r * D + dstu * 8] = q.u;

        float s8 = v0.x*v0.x + v0.y*v0.y + v0.z*v0.z + v0.w*v0.w
                 + v1.x*v1.x + v1.y*v1.y + v1.z*v1.z + v1.w*v1.w;
        ssq += s8;
        cs[0] += v0.x; cs[1] += v0.y; cs[2] += v0.z; cs[3] += v0.w;
        cs[4] += v1.x; cs[5] += v1.y; cs[6] += v1.z; cs[7] += v1.w;
        float rsum = s8;
        for (int off = 32; off > 0; off >>= 1) rsum += __shfl_down(rsum, off);
        if (l == 0) sq[r] = rsum;
    }
#pragma unroll
    for (int j = 0; j < 8; ++j) cs_lds[w][l * 8 + j] = cs[j];
    for (int off = 32; off > 0; off >>= 1) ssq += __shfl_down(ssq, off);
    __shared__ float wssq[4];
    if (l == 0) wssq[w] = ssq;
    __syncthreads();
    int c0 = t * 2;
    float a = cs_lds[0][c0] + cs_lds[1][c0] + cs_lds[2][c0] + cs_lds[3][c0];
    float b = cs_lds[0][c0+1] + cs_lds[1][c0+1] + cs_lds[2][c0+1] + cs_lds[3][c0+1];
    atomicAdd(&colsum[c0], a);
    atomicAdd(&colsum[c0 + 1], b);
    if (t == 0) atomicAdd(sumsq, (double)(wssq[0] + wssq[1] + wssq[2] + wssq[3]));
}

// --- Pass B: bandwidth scalar ---
__global__ void bw_kernel(const float* __restrict__ colsum, const double* __restrict__ sumsq,
                          float* __restrict__ inv16bw) {
    __shared__ double red[512];
    int c = threadIdx.x;
    double v = (double)colsum[c];
    red[c] = v * v;
    __syncthreads();
    for (int s = 256; s > 0; s >>= 1) {
        if (c < s) red[c] += red[c + s];
        __syncthreads();
    }
    if (c == 0) {
        double m = (double)NROWS;
        double sumL2 = 2.0 * m * sumsq[0] - 2.0 * red[0];
        double bw = sumL2 / (m * m - m);
        bw = bw / 4.0;  // / KERNEL_MUL^(KERNEL_NUM//2)
        inv16bw[0] = (float)(1.0 / (16.0 * bw));
    }
}

// --- Pass C: fp8 MFMA pairwise kernel, R5 skeleton (no tickets, no fences) ---
__global__ __launch_bounds__(256)
void mmd_main(const unsigned char* __restrict__ tot8,
              const float* __restrict__ sq, const float* __restrict__ inv16bw_p,
              double* __restrict__ S) {
    int b = blockIdx.x;
    int ti = (b & 7) * (NTRI / 8) + (b >> 3);   // XCD swizzle (2080 % 8 == 0)
    int bi = (int)(64.5f - sqrtf(64.5f * 64.5f - 2.0f * (float)ti));
    if (bi < 0) bi = 0;
    while (bi > 0 && bi * NB - bi * (bi - 1) / 2 > ti) --bi;
    while ((bi + 1) * NB - (bi + 1) * bi / 2 <= ti) ++bi;
    int bj = bi + (ti - (bi * NB - bi * (bi - 1) / 2));

    // LDS: row-major fp8 tile [128 rows][128 B], 8B-units XOR-swizzled (baked in global)
    __shared__ __align__(16) unsigned char As[BM * BKB];   // 16 KB
    __shared__ __align__(16) unsigned char Bs[BM * BKB];   // 16 KB

    int t = threadIdx.x, l = t & 63, w = t >> 6;
    int wr = w >> 1, wc = w & 1;       // 2x2 wave grid, 64x64 out each
    int m = l & 15, kg = l >> 4;

    const unsigned char* ab = tot8 + (size_t)(bi * BM) * D;
    const unsigned char* bb = tot8 + (size_t)(bj * BM) * D;

    f32x4 acc[4][4];
#pragma unroll
    for (int i = 0; i < 4; ++i)
#pragma unroll
        for (int j = 0; j < 4; ++j)
            acc[i][j] = (f32x4){0.f, 0.f, 0.f, 0.f};

    for (int kt = 0; kt < NKT; ++kt) {
        __syncthreads();   // previous iteration's LDS reads done
        // 1024 16-B chunks per matrix (128 rows x 8 chunks); 4 per thread; verbatim copy
#pragma unroll
        for (int i = 0; i < 4; ++i) {
            int g = i * 256 + t;
            int row = g >> 3, ch = g & 7;
            __builtin_amdgcn_global_load_lds(
                (const __attribute__((address_space(1))) void*)(ab + (size_t)row * D + kt * BKB + ch * 16),
                (__attribute__((address_space(3))) void*)(As + g * 16),
                16, 0, 0);
            __builtin_amdgcn_global_load_lds(
                (const __attribute__((address_space(1))) void*)(bb + (size_t)row * D + kt * BKB + ch * 16),
                (__attribute__((address_space(3))) void*)(Bs + g * 16),
                16, 0, 0);
        }
        __syncthreads();   // drains vmcnt(0): tile ready

#pragma unroll
        for (int ks = 0; ks < 4; ++ks) {   // 4 x K=32 fp8 MFMA slices per tile
            long af[4], bfr[4];
#pragma unroll
            for (int fi = 0; fi < 4; ++fi) {
                int row = wr * 64 + fi * 16 + m;
                int unit = (ks * 4 + kg) ^ m;          // un-swizzle on read
                af[fi] = *(const long*)&As[row * BKB + unit * 8];
            }
#pragma unroll
            for (int fj = 0; fj < 4; ++fj) {
                int row = wc * 64 + fj * 16 + m;
                int unit = (ks * 4 + kg) ^ m;
                bfr[fj] = *(const long*)&Bs[row * BKB + unit * 8];
            }
#pragma unroll
            for (int fi = 0; fi < 4; ++fi)
#pragma unroll
                for (int fj = 0; fj < 4; ++fj)
                    acc[fi][fj] = __builtin_amdgcn_mfma_f32_16x16x32_fp8_fp8(af[fi], bfr[fj], acc[fi][fj], 0, 0, 0);
        }
    }

    // Epilogue: L2 -> 5-kernel sum (1 exp + 4 squarings); exact diagonal substitution
    float inv16bw = inv16bw_p[0];
    float coef = ((bi == bj) ? 1.f : 2.f) * (((bi < NB / 2) == (bj < NB / 2)) ? 1.f : -1.f);

    float sqj[4];
#pragma unroll
    for (int fj = 0; fj < 4; ++fj) sqj[fj] = sq[bj * BM + wc * 64 + fj * 16 + m];
    int ib = bi * BM + wr * 64 + kg * 4;

    float local = 0.f;
#pragma unroll
    for (int fi = 0; fi < 4; ++fi) {
        float sqi[4];
#pragma unroll
        for (int j = 0; j < 4; ++j) sqi[j] = sq[ib + fi * 16 + j];
#pragma unroll
        for (int fj = 0; fj < 4; ++fj) {
#pragma unroll
            for (int j = 0; j < 4; ++j) {
                float L2 = sqi[j] + sqj[fj] - 2.f * acc[fi][fj][j];
                float u = __expf(-L2 * inv16bw);   // e^{-t/16}
                float ks = u;
                u *= u; ks += u;   // e^{-t/8}
                u *= u; ks += u;   // e^{-t/4}
                u *= u; ks += u;   // e^{-t/2}
                u *= u; ks += u;   // e^{-t}
                if (bi == bj) {
                    int ig = wr * 64 + fi * 16 + kg * 4 + j;
                    int jg = wc * 64 + fj * 16 + m;
                    if (ig == jg) ks = 5.0f;  // exact diagonal: L2 == 0 -> 5 kernels of 1
                }
                local += ks;
            }
        }
    }
    local *= coef;

    for (int off = 32; off > 0; off >>= 1) local += __shfl_down(local, off);
    __shared__ float wsum[4];
    if ((t & 63) == 0) wsum[t >> 6] = local;
    __syncthreads();
    if (t == 0) {
        float bsum = wsum[0] + wsum[1] + wsum[2] + wsum[3];
        atomicAdd(S, (double)bsum);
    }
}

__global__ void finalize_kernel(const double* __restrict__ S, float* __restrict__ out) {
    out[0] = (float)(S[0] / ((double)NHALF * (double)NHALF));
}

extern "C" void kernel_launch(void* const* d_in, const int* in_sizes, int n_in,
                              void* d_out, int out_size, void* d_ws, size_t ws_size,
                              hipStream_t stream) {
    const float* src = (const float*)d_in[0];
    const float* tgt = (const float*)d_in[1];
    float* out = (float*)d_out;
    char* ws = (char*)d_ws;

    // ws layout
    unsigned char* tot8 = (unsigned char*)ws;              // 4 MB (8192*512 fp8)
    float*  sq      = (float*)(ws + 4194304);              // 32768 B
    float*  colsum  = (float*)(ws + 4194304 + 32768);      // 2048 B
    double* sumsq   = (double*)(ws + 4194304 + 34816);     // 8 B
    double* S       = (double*)(ws + 4194304 + 34824);     // 8 B
    float*  inv16bw = (float*)(ws + 4194304 + 34832);      // 4 B

    // zero accumulators (ws poisoned 0xAA, not re-poisoned between replays)
    hipMemsetAsync(ws + 4194304 + 32768, 0, 2068, stream);

    conv_stats<<<128, 256, 0, stream>>>(src, tgt, tot8, sq, colsum, sumsq);
    bw_kernel<<<1, 512, 0, stream>>>(colsum, sumsq, inv16bw);
    mmd_main<<<NTRI, 256, 0, stream>>>(tot8, sq, inv16bw, S);
    finalize_kernel<<<1, 1, 0, stream>>>(S, out);
}

// Round 16
// 73.133 us; speedup vs baseline: 2.3110x; 1.0082x over previous
//
#include <hip/hip_runtime.h>
#include <hip/hip_fp8.h>

#define NHALF 4096
#define NROWS 8192
#define D 512
#define BM 128
#define BKB 128                    // K-depth per tile in fp8 bytes
#define NKT (D / BKB)              // 4 K-steps
#define NB (NROWS / BM)            // 64
#define NTRI (NB * (NB + 1) / 2)   // 2080 (divisible by 8)

typedef float f32x4 __attribute__((ext_vector_type(4)));
typedef int   v8i   __attribute__((ext_vector_type(8)));

__device__ __forceinline__ const float* row_ptr(const float* __restrict__ src,
                                                const float* __restrict__ tgt, int r) {
    return (r < NHALF) ? (src + (size_t)r * D) : (tgt + (size_t)(r - NHALF) * D);
}

// --- Pass A: fused convert fp32->fp8 e4m3 (XOR-swizzle baked) + rowsq + colsum + sumsq ---
// 256 blocks x 256 threads; block handles 32 rows, each wave 8 rows.
__global__ __launch_bounds__(256)
void conv_stats(const float* __restrict__ src, const float* __restrict__ tgt,
                unsigned char* __restrict__ tot8, float* __restrict__ sq,
                float* __restrict__ colsum, double* __restrict__ sumsq) {
    __shared__ float cs_lds[4][512];
    int t = threadIdx.x, l = t & 63, w = t >> 6;
    int rbase = blockIdx.x * 32 + w * 8;

    float cs[8] = {0.f, 0.f, 0.f, 0.f, 0.f, 0.f, 0.f, 0.f};
    float ssq = 0.f;

    for (int rr = 0; rr < 8; ++rr) {
        int r = rbase + rr;
        const float* p = row_ptr(src, tgt, r) + l * 8;
        float4 v0 = *(const float4*)p;
        float4 v1 = *(const float4*)(p + 4);
        // pack 8 fp8 e4m3 bytes (unit l of row r); store at XOR-swizzled unit slot
        union { unsigned long long u; unsigned char b[8]; } q;
        q.b[0] = __hip_fp8_e4m3(v0.x).__x; q.b[1] = __hip_fp8_e4m3(v0.y).__x;
        q.b[2] = __hip_fp8_e4m3(v0.z).__x; q.b[3] = __hip_fp8_e4m3(v0.w).__x;
        q.b[4] = __hip_fp8_e4m3(v1.x).__x; q.b[5] = __hip_fp8_e4m3(v1.y).__x;
        q.b[6] = __hip_fp8_e4m3(v1.z).__x; q.b[7] = __hip_fp8_e4m3(v1.w).__x;
        unsigned dstu = (unsigned)((l & 48) | ((l & 15) ^ (r & 15)));
        *(unsigned long long*)&tot8[(size_t)r * D + dstu * 8] = q.u;

        float s8 = v0.x*v0.x + v0.y*v0.y + v0.z*v0.z + v0.w*v0.w
                 + v1.x*v1.x + v1.y*v1.y + v1.z*v1.z + v1.w*v1.w;
        ssq += s8;
        cs[0] += v0.x; cs[1] += v0.y; cs[2] += v0.z; cs[3] += v0.w;
        cs[4] += v1.x; cs[5] += v1.y; cs[6] += v1.z; cs[7] += v1.w;
        float rsum = s8;
        for (int off = 32; off > 0; off >>= 1) rsum += __shfl_down(rsum, off);
        if (l == 0) sq[r] = rsum;
    }
#pragma unroll
    for (int j = 0; j < 8; ++j) cs_lds[w][l * 8 + j] = cs[j];
    for (int off = 32; off > 0; off >>= 1) ssq += __shfl_down(ssq, off);
    __shared__ float wssq[4];
    if (l == 0) wssq[w] = ssq;
    __syncthreads();
    int c0 = t * 2;
    float a = cs_lds[0][c0] + cs_lds[1][c0] + cs_lds[2][c0] + cs_lds[3][c0];
    float b = cs_lds[0][c0+1] + cs_lds[1][c0+1] + cs_lds[2][c0+1] + cs_lds[3][c0+1];
    atomicAdd(&colsum[c0], a);
    atomicAdd(&colsum[c0 + 1], b);
    if (t == 0) atomicAdd(sumsq, (double)(wssq[0] + wssq[1] + wssq[2] + wssq[3]));
}

// --- Pass B: fp8 MX-scaled MFMA pairwise kernel (unit scales), bw folded into prologue ---
__global__ __launch_bounds__(256, 3)
void mmd_main(const unsigned char* __restrict__ tot8,
              const float* __restrict__ sq, const float* __restrict__ colsum,
              const double* __restrict__ sumsq, double* __restrict__ S) {
    int b = blockIdx.x;
    int ti = (b & 7) * (NTRI / 8) + (b >> 3);   // XCD swizzle (2080 % 8 == 0)
    int bi = (int)(64.5f - sqrtf(64.5f * 64.5f - 2.0f * (float)ti));
    if (bi < 0) bi = 0;
    while (bi > 0 && bi * NB - bi * (bi - 1) / 2 > ti) --bi;
    while ((bi + 1) * NB - (bi + 1) * bi / 2 <= ti) ++bi;
    int bj = bi + (ti - (bi * NB - bi * (bi - 1) / 2));

    // LDS: row-major fp8 tile [128 rows][128 B], 8B-units XOR-swizzled (baked in global)
    __shared__ __align__(16) unsigned char As[BM * BKB];   // 16 KB
    __shared__ __align__(16) unsigned char Bs[BM * BKB];   // 16 KB

    int t = threadIdx.x, l = t & 63, w = t >> 6;
    int wr = w >> 1, wc = w & 1;       // 2x2 wave grid, 64x64 out each
    int m = l & 15, kg = l >> 4;

    const unsigned char* ab = tot8 + (size_t)(bi * BM) * D;
    const unsigned char* bb = tot8 + (size_t)(bj * BM) * D;

    auto stage = [&](int kt) {
#pragma unroll
        for (int i = 0; i < 4; ++i) {
            int g = i * 256 + t;
            int row = g >> 3, ch = g & 7;
            __builtin_amdgcn_global_load_lds(
                (const __attribute__((address_space(1))) void*)(ab + (size_t)row * D + kt * BKB + ch * 16),
                (__attribute__((address_space(3))) void*)(As + g * 16),
                16, 0, 0);
            __builtin_amdgcn_global_load_lds(
                (const __attribute__((address_space(1))) void*)(bb + (size_t)row * D + kt * BKB + ch * 16),
                (__attribute__((address_space(3))) void*)(Bs + g * 16),
                16, 0, 0);
        }
    };

    // Issue first tile's loads, then compute bandwidth under their flight.
    stage(0);

    float c1 = colsum[t], c2 = colsum[t + 256];
    float part = c1 * c1 + c2 * c2;
    for (int off = 32; off > 0; off >>= 1) part += __shfl_down(part, off);
    __shared__ float bwl[4];
    if (l == 0) bwl[w] = part;
    __syncthreads();
    float sumcol2 = bwl[0] + bwl[1] + bwl[2] + bwl[3];
    double md = (double)NROWS;
    double sumL2 = 2.0 * md * sumsq[0] - 2.0 * (double)sumcol2;
    double bwv = sumL2 / (md * md - md) / 4.0;   // / KERNEL_MUL^(KERNEL_NUM//2)
    float inv16bw = (float)(1.0 / (16.0 * bwv));

    f32x4 acc[4][4];
#pragma unroll
    for (int i = 0; i < 4; ++i)
#pragma unroll
        for (int j = 0; j < 4; ++j)
            acc[i][j] = (f32x4){0.f, 0.f, 0.f, 0.f};

    __syncthreads();   // drains vmcnt(0): tile 0 ready

    for (int kt = 0; kt < NKT; ++kt) {
        // K=128 fragments: 4 x b64 per row, read-side XOR recovers original chunks
        union Frag { v8i v; long q[4]; };
        Frag fa[4];
#pragma unroll
        for (int fi = 0; fi < 4; ++fi) {
            int row = wr * 64 + fi * 16 + m;
#pragma unroll
            for (int q = 0; q < 4; ++q) {
                int unit = (q * 4 + kg) ^ m;
                fa[fi].q[q] = *(const long*)&As[row * BKB + unit * 8];
            }
        }
#pragma unroll
        for (int fj = 0; fj < 4; ++fj) {
            Frag fb;
            int row = wc * 64 + fj * 16 + m;
#pragma unroll
            for (int q = 0; q < 4; ++q) {
                int unit = (q * 4 + kg) ^ m;
                fb.q[q] = *(const long*)&Bs[row * BKB + unit * 8];
            }
#pragma unroll
            for (int fi = 0; fi < 4; ++fi)
                acc[fi][fj] = __builtin_amdgcn_mfma_scale_f32_16x16x128_f8f6f4(
                    fa[fi].v, fb.v, acc[fi][fj], 0, 0,
                    0, 0x7F7F7F7F, 0, 0x7F7F7F7F);   // unit scales (E8M0 1.0)
        }
        if (kt + 1 < NKT) {
            __syncthreads();   // all waves done reading this tile
            stage(kt + 1);
            __syncthreads();   // drains vmcnt(0): next tile ready
        }
    }

    // Epilogue: L2 -> 5-kernel sum (1 exp + 4 squarings); exact diagonal substitution
    float coef = ((bi == bj) ? 1.f : 2.f) * (((bi < NB / 2) == (bj < NB / 2)) ? 1.f : -1.f);

    float sqj[4];
#pragma unroll
    for (int fj = 0; fj < 4; ++fj) sqj[fj] = sq[bj * BM + wc * 64 + fj * 16 + m];
    int ib = bi * BM + wr * 64 + kg * 4;

    float local = 0.f;
#pragma unroll
    for (int fi = 0; fi < 4; ++fi) {
        float sqi[4];
#pragma unroll
        for (int j = 0; j < 4; ++j) sqi[j] = sq[ib + fi * 16 + j];
#pragma unroll
        for (int fj = 0; fj < 4; ++fj) {
#pragma unroll
            for (int j = 0; j < 4; ++j) {
                float L2 = sqi[j] + sqj[fj] - 2.f * acc[fi][fj][j];
                float u = __expf(-L2 * inv16bw);   // e^{-t/16}
                float ks = u;
                u *= u; ks += u;   // e^{-t/8}
                u *= u; ks += u;   // e^{-t/4}
                u *= u; ks += u;   // e^{-t/2}
                u *= u; ks += u;   // e^{-t}
                if (bi == bj) {
                    int ig = wr * 64 + fi * 16 + kg * 4 + j;
                    int jg = wc * 64 + fj * 16 + m;
                    if (ig == jg) ks = 5.0f;  // exact diagonal: L2 == 0 -> 5 kernels of 1
                }
                local += ks;
            }
        }
    }
    local *= coef;

    for (int off = 32; off > 0; off >>= 1) local += __shfl_down(local, off);
    __shared__ float wsum[4];
    if ((t & 63) == 0) wsum[t >> 6] = local;
    __syncthreads();
    if (t == 0) {
        float bsum = wsum[0] + wsum[1] + wsum[2] + wsum[3];
        atomicAdd(S, (double)bsum);
    }
}

__global__ void finalize_kernel(const double* __restrict__ S, float* __restrict__ out) {
    out[0] = (float)(S[0] / ((double)NHALF * (double)NHALF));
}

extern "C" void kernel_launch(void* const* d_in, const int* in_sizes, int n_in,
                              void* d_out, int out_size, void* d_ws, size_t ws_size,
                              hipStream_t stream) {
    const float* src = (const float*)d_in[0];
    const float* tgt = (const float*)d_in[1];
    float* out = (float*)d_out;
    char* ws = (char*)d_ws;

    // ws layout
    unsigned char* tot8 = (unsigned char*)ws;              // 4 MB (8192*512 fp8)
    float*  sq      = (float*)(ws + 4194304);              // 32768 B
    float*  colsum  = (float*)(ws + 4194304 + 32768);      // 2048 B
    double* sumsq   = (double*)(ws + 4194304 + 34816);     // 8 B
    double* S       = (double*)(ws + 4194304 + 34824);     // 8 B

    // zero accumulators (ws poisoned 0xAA, not re-poisoned between replays)
    hipMemsetAsync(ws + 4194304 + 32768, 0, 2064, stream);

    conv_stats<<<256, 256, 0, stream>>>(src, tgt, tot8, sq, colsum, sumsq);
    mmd_main<<<NTRI, 256, 0, stream>>>(tot8, sq, colsum, sumsq, S);
    finalize_kernel<<<1, 1, 0, stream>>>(S, out);
}